// Round 1
// 832.319 us; speedup vs baseline: 1.2301x; 1.2301x over previous
//
#include <hip/hip_runtime.h>
#include <hip/hip_bf16.h>
#include <cstdint>

// LISTA: Z = eta(X@We^T + Z@S^T), 16 unrolled steps. B=16384, n=256, m=1024.
// This version: 256x256-tile 8-phase counted-vmcnt schedule (T2+T3+T4+T5),
// 8 waves (2Mx4N), BK=64, 128 KiB double-buffered LDS, XOR-swizzled.
// B = X@We^T is NOT materialized: every step computes the K-concatenated GEMM
// C = [X,Z] @ [We,S]^T (K = 256 + 1024 = 1280, NT = 20 K-tiles), so the fp32
// B re-read (64 MB/step) disappears; X(8MB)/S(2MB) stay L3/L2 resident.
// Grid 64x4 = 256 blocks = exactly 1 block/CU (no tail).

typedef __attribute__((ext_vector_type(8))) short short8;   // 8 x bf16
typedef __attribute__((ext_vector_type(4))) float floatx4;  // mfma acc

__device__ __forceinline__ void g2lds16(const void* g, void* l) {
    __builtin_amdgcn_global_load_lds(
        (const __attribute__((address_space(1))) uint32_t*)(uintptr_t)g,
        (__attribute__((address_space(3))) uint32_t*)(uintptr_t)l,
        16, 0, 0);
}

#define VM4  asm volatile("s_waitcnt vmcnt(4)" ::: "memory")
#define VM0  asm volatile("s_waitcnt vmcnt(0)" ::: "memory")
#define NOPX ((void)0)

// A-fragment loads: 4 m-frags x 2 k-slices from A-half HH of buffer CB.
#define LOAD_A(CB, HH) do { \
    const char* ap_ = &lds[CB][0][HH][0] + arow; \
    _Pragma("unroll") \
    for (int mi_ = 0; mi_ < 4; ++mi_) { \
        af[mi_][0] = *(const short8*)(ap_ + mi_*2048 + ck0); \
        af[mi_][1] = *(const short8*)(ap_ + mi_*2048 + ck1); \
    } } while (0)

// B-fragment loads: 2 n-frags x 2 k-slices from B-half HH of buffer CB.
#define LOAD_B(CB, HH, BF) do { \
    const char* bp_ = &lds[CB][1][HH][0] + brow; \
    _Pragma("unroll") \
    for (int ni_ = 0; ni_ < 2; ++ni_) { \
        BF[ni_][0] = *(const short8*)(bp_ + ni_*2048 + ck0); \
        BF[ni_][1] = *(const short8*)(bp_ + ni_*2048 + ck1); \
    } } while (0)

// One phase: {ds-reads | stage issue} ; bar ; lgkmcnt(0) ; 16 MFMA ; [vmcnt] ; bar
#define PHASE(LD1, LD2, STG, QM, QN, BF, VMW) do { \
    LD1; LD2; STG; \
    __builtin_amdgcn_s_barrier(); \
    asm volatile("s_waitcnt lgkmcnt(0)" ::: "memory"); \
    __builtin_amdgcn_sched_barrier(0); \
    __builtin_amdgcn_s_setprio(1); \
    _Pragma("unroll") \
    for (int mi_ = 0; mi_ < 4; ++mi_) \
    _Pragma("unroll") \
    for (int ni_ = 0; ni_ < 2; ++ni_) \
    _Pragma("unroll") \
    for (int kk_ = 0; kk_ < 2; ++kk_) \
        acc[(QM)*4+mi_][(QN)*2+ni_] = __builtin_amdgcn_mfma_f32_16x16x32_bf16( \
            af[mi_][kk_], BF[ni_][kk_], acc[(QM)*4+mi_][(QN)*2+ni_], 0, 0, 0); \
    __builtin_amdgcn_s_setprio(0); \
    VMW; \
    __builtin_amdgcn_s_barrier(); \
    __builtin_amdgcn_sched_barrier(0); \
} while (0)

// Tiles 0..NTX-1 come from (Ax,Wx) with row stride NTX*128 bytes;
// tiles NTX..NTX+NTZ-1 from (Az,Wz) with row stride NTZ*128 bytes.
// C[i,j] = sum_k A[i,k]*W[j,k]; output eta(C) (bf16, or fp32 if LAST).
template<int NTX, int NTZ, bool LAST>
__global__ void __launch_bounds__(512, 2)
lista_step(const unsigned short* __restrict__ Ax,
           const unsigned short* __restrict__ Wx,
           const unsigned short* __restrict__ Az,
           const unsigned short* __restrict__ Wz,
           const float* __restrict__ theta,
           unsigned short* __restrict__ Zout,
           float* __restrict__ Fout)
{
    constexpr int NT  = NTX + NTZ;     // total K-tiles of 64
    constexpr int NI  = NT / 2;        // main iterations (2 K-tiles each)
    constexpr int KBX = NTX * 128;     // X/We row stride (bytes)
    constexpr int KBZ = NTZ * 128;     // Z/S  row stride (bytes)
    constexpr int N   = 1024;

    // [buf][A=0/B=1][half][16KB]; half = permuted 128-row group so each half
    // is LDS-read in exactly one phase (A: bit6 of row; B: bit5 of row).
    __shared__ __align__(128) char lds[2][2][2][16384];

    const int t    = threadIdx.x;      // 0..511
    const int lane = t & 63;
    const int wave = t >> 6;           // 0..7
    const int wm   = wave >> 2;        // 0..1  (M half)
    const int wn   = wave & 3;         // 0..3  (N quarter)
    const int bm   = blockIdx.x;       // 0..63
    const int bn   = blockIdx.y;       // 0..3

    const char* Xb = (const char*)Ax + (size_t)bm * 256 * KBX;
    const char* Wb = (const char*)Wx + (size_t)bn * 256 * KBX;
    const char* Zb = (const char*)Az + (size_t)bm * 256 * KBZ;
    const char* Sb = (const char*)Wz + (size_t)bn * 256 * KBZ;

    // ---- staging constants: thread t handles chunks I = c*512+t (c=0,1),
    // compacted row rho = I>>3, slot = I&7, global k-chunk = slot ^ (rho&7).
    const int u    = t >> 3;                       // 0..63
    const int gb16 = ((t & 7) ^ (u & 7)) << 4;     // swizzled k-chunk byte off
    const int rA0  = u;                            // A: row = rA0+64h (+128 c=1)
    const int rB0  = (u & 31) + 2 * (u & 32);      // B: row = rB0+32h (+128 c=1)

    // ---- fragment-read constants
    const int rl   = lane & 15;
    const int q    = lane >> 4;                    // k-quad
    const int ck0  = ((q ^ (rl & 7)) << 4);        // kk=0 chunk byte (swizzled)
    const int ck1  = (((4 + q) ^ (rl & 7)) << 4);  // kk=1
    const int arow = (wm * 64 + rl) * 128;         // A compacted-row byte base
    const int brow = (wn * 32 + rl) * 128;         // B compacted-row byte base

    floatx4 acc[8][4];
#pragma unroll
    for (int i = 0; i < 8; ++i)
#pragma unroll
        for (int j = 0; j < 4; ++j) acc[i][j] = (floatx4){0.f, 0.f, 0.f, 0.f};

    short8 af[4][2], bf0[2][2], bf1[2][2];

    auto STAGE_A = [&](int buf, int h, int kt) {
        const char* base; int kb, ko;
        if (NTZ == 0 || kt < NTX) { base = Xb; kb = KBX; ko = kt * 128; }
        else                      { base = Zb; kb = KBZ; ko = (kt - NTX) * 128; }
        char* lp = &lds[buf][0][h][0] + t * 16;
        const size_t go = (size_t)(rA0 + 64 * h) * kb + ko + gb16;
        g2lds16(base + go, lp);
        g2lds16(base + go + (size_t)128 * kb, lp + 8192);
    };
    auto STAGE_B = [&](int buf, int h, int kt) {
        const char* base; int kb, ko;
        if (NTZ == 0 || kt < NTX) { base = Wb; kb = KBX; ko = kt * 128; }
        else                      { base = Sb; kb = KBZ; ko = (kt - NTX) * 128; }
        char* lp = &lds[buf][1][h][0] + t * 16;
        const size_t go = (size_t)(rB0 + 32 * h) * kb + ko + gb16;
        g2lds16(base + go, lp);
        g2lds16(base + go + (size_t)128 * kb, lp + 8192);
    };

    // ---- prologue: tile0 fully + tile1 {A.h0, B.h1}; wait tile0; barrier.
    STAGE_A(0, 0, 0); STAGE_B(0, 0, 0); STAGE_A(0, 1, 0); STAGE_B(0, 1, 0);
    STAGE_A(1, 0, 1); STAGE_B(1, 1, 1);
    VM4;                                   // tile0 landed; 2 half-tiles in flight
    __builtin_amdgcn_s_barrier();
    __builtin_amdgcn_sched_barrier(0);

    // ---- main loop: iteration i computes tiles 2i (buf0) and 2i+1 (buf1).
    // Quadrant order per tile: (0,0)->(0,1)->(1,1)->(1,0) with A/B register
    // reuse (24 ds_read_b128 per tile per wave). Stage schedule (1 half/phase)
    // satisfies: issue after old occupant's last LDS read; landing enforced by
    // VM4 at phases 3 and 7 (4-in-flight steady state, never vmcnt(0)).
#pragma unroll 1
    for (int it = 0; it < NI - 1; ++it) {
        const int t1 = 2 * it + 1, t2 = 2 * it + 2, t3 = 2 * it + 3;
        PHASE(LOAD_A(0,0), LOAD_B(0,0,bf0), STAGE_A(1,1,t1), 0,0, bf0, NOPX);
        PHASE(LOAD_B(0,1,bf1), NOPX,        STAGE_B(1,0,t1), 0,1, bf1, NOPX);
        PHASE(LOAD_A(0,1), NOPX,            STAGE_A(0,0,t2), 1,1, bf1, NOPX);
        PHASE(NOPX, NOPX,                   STAGE_B(0,1,t2), 1,0, bf0, VM4);
        PHASE(LOAD_A(1,0), LOAD_B(1,0,bf0), STAGE_B(0,0,t2), 0,0, bf0, NOPX);
        PHASE(LOAD_B(1,1,bf1), NOPX,        STAGE_A(0,1,t2), 0,1, bf1, NOPX);
        PHASE(LOAD_A(1,1), NOPX,            STAGE_A(1,0,t3), 1,1, bf1, NOPX);
        PHASE(NOPX, NOPX,                   STAGE_B(1,1,t3), 1,0, bf0, VM4);
    }
    {   // last iteration: finish staging tile NT-1, no future tiles, drain.
        const int t1 = NT - 1;
        PHASE(LOAD_A(0,0), LOAD_B(0,0,bf0), STAGE_A(1,1,t1), 0,0, bf0, NOPX);
        PHASE(LOAD_B(0,1,bf1), NOPX,        STAGE_B(1,0,t1), 0,1, bf1, NOPX);
        PHASE(LOAD_A(0,1), NOPX,            NOPX,            1,1, bf1, NOPX);
        PHASE(NOPX, NOPX,                   NOPX,            1,0, bf0, VM0);
        PHASE(LOAD_A(1,0), LOAD_B(1,0,bf0), NOPX,            0,0, bf0, NOPX);
        PHASE(LOAD_B(1,1,bf1), NOPX,        NOPX,            0,1, bf1, NOPX);
        PHASE(LOAD_A(1,1), NOPX,            NOPX,            1,1, bf1, NOPX);
        PHASE(NOPX, NOPX,                   NOPX,            1,0, bf0, NOPX);
    }

    // ---- epilogue: C/D layout col = lane&15, row = (lane>>4)*4 + reg
    const int colb = bn * 256 + wn * 64 + (lane & 15);
    const int rowb = bm * 256 + wm * 128 + ((lane >> 4) << 2);
#pragma unroll
    for (int ni = 0; ni < 4; ++ni) {
        const float th = theta[colb + ni * 16];
#pragma unroll
        for (int mi = 0; mi < 8; ++mi) {
#pragma unroll
            for (int v = 0; v < 4; ++v) {
                const size_t idx = (size_t)(rowb + mi * 16 + v) * N + (colb + ni * 16);
                const float c = acc[mi][ni][v];
                const float a = fabsf(c) - th;
                const float z = a > 0.f ? (c > 0.f ? a : -a) : 0.f;
                if constexpr (LAST) {
                    Fout[idx] = z;
                } else {
                    __hip_bfloat16 hb = __float2bfloat16(z);
                    Zout[idx] = *(const unsigned short*)&hb;
                }
            }
        }
    }
}

__global__ void __launch_bounds__(256)
cvt4(const float* __restrict__ s, unsigned short* __restrict__ d, int n4)
{
    const int i = blockIdx.x * blockDim.x + threadIdx.x;
    if (i < n4) {
        const float4 v = ((const float4*)s)[i];
        ushort4 o;
        __hip_bfloat16 b;
        b = __float2bfloat16(v.x); o.x = *(unsigned short*)&b;
        b = __float2bfloat16(v.y); o.y = *(unsigned short*)&b;
        b = __float2bfloat16(v.z); o.z = *(unsigned short*)&b;
        b = __float2bfloat16(v.w); o.w = *(unsigned short*)&b;
        ((ushort4*)d)[i] = o;
    }
}

extern "C" void kernel_launch(void* const* d_in, const int* in_sizes, int n_in,
                              void* d_out, int out_size, void* d_ws, size_t ws_size,
                              hipStream_t stream) {
    (void)in_sizes; (void)n_in; (void)out_size; (void)ws_size;
    const float* X     = (const float*)d_in[0];  // 16384 x 256
    const float* We    = (const float*)d_in[1];  // 1024 x 256
    const float* S     = (const float*)d_in[2];  // 1024 x 1024
    const float* theta = (const float*)d_in[3];  // 1024
    float* out = (float*)d_out;                  // 16384 x 1024 fp32

    char* ws = (char*)d_ws;
    unsigned short* S_bf  = (unsigned short*)(ws);                           //  2 MB
    unsigned short* X_bf  = (unsigned short*)(ws + (size_t)2  * 1048576);    //  8 MB
    unsigned short* We_bf = (unsigned short*)(ws + (size_t)10 * 1048576);    // 0.5 MB
    unsigned short* Za    = (unsigned short*)(ws + (size_t)11 * 1048576);    // 32 MB
    unsigned short* Zb    = (unsigned short*)(ws + (size_t)43 * 1048576);    // 32 MB (total 75 MB)

    cvt4<<<dim3(1024), dim3(256), 0, stream>>>(S,  S_bf,  1024 * 1024 / 4);
    cvt4<<<dim3(4096), dim3(256), 0, stream>>>(X,  X_bf,  16384 * 256 / 4);
    cvt4<<<dim3(256),  dim3(256), 0, stream>>>(We, We_bf, 1024 * 256 / 4);

    const dim3 grid(64, 4), blk(512);

    // Z0 = eta(X @ We^T)            (K = 256)
    lista_step<4, 0, false><<<grid, blk, 0, stream>>>(
        X_bf, We_bf, nullptr, nullptr, theta, Za, nullptr);

    // steps 1..15: Z = eta([X,Z] @ [We,S]^T)   (K = 1280), ping-pong bf16
    unsigned short* zin = Za;
    unsigned short* zout = Zb;
    for (int tstep = 1; tstep <= 15; ++tstep) {
        lista_step<4, 16, false><<<grid, blk, 0, stream>>>(
            X_bf, We_bf, zin, S_bf, theta, zout, nullptr);
        unsigned short* tmp = zin; zin = zout; zout = tmp;
    }
    // step 16: write fp32 output directly
    lista_step<4, 16, true><<<grid, blk, 0, stream>>>(
        X_bf, We_bf, zin, S_bf, theta, nullptr, out);
}

// Round 2
// 771.653 us; speedup vs baseline: 1.3268x; 1.0786x over previous
//
#include <hip/hip_runtime.h>
#include <hip/hip_bf16.h>
#include <cstdint>

// LISTA: Z = eta(X@We^T + Z@S^T), 16 unrolled steps. B=16384, n=256, m=1024.
// 256x256-tile 8-phase counted-vmcnt schedule (T2+T3+T4+T5), 8 waves (2Mx4N),
// BK=64, 128 KiB double-buffered LDS, XOR-swizzled. B = X@We^T not materialized:
// each step computes C = [X,Z] @ [We,S]^T (K = 1280, NT = 20 K-tiles).
// Round-2 changes vs round-1:
//  (a) deep prefetch: each tile is staged entirely in the phase window of the
//      buffer's previous occupant (stage at +1..+3 phases after region-free),
//      giving a uniform 4-phase lead and constant vmcnt(8) ledger (16 in
//      flight -> drain oldest 8 = exactly the tile consumed next).
//  (b) epilogue loop reorder (row outer, ni inner) so each 128B output line is
//      completed by 4 consecutive 32B stores (fixes 80MB->~33MB write RMW).

typedef __attribute__((ext_vector_type(8))) short short8;   // 8 x bf16
typedef __attribute__((ext_vector_type(4))) float floatx4;  // mfma acc

__device__ __forceinline__ void g2lds16(const void* g, void* l) {
    __builtin_amdgcn_global_load_lds(
        (const __attribute__((address_space(1))) uint32_t*)(uintptr_t)g,
        (__attribute__((address_space(3))) uint32_t*)(uintptr_t)l,
        16, 0, 0);
}

#define VM8  asm volatile("s_waitcnt vmcnt(8)" ::: "memory")
#define VM0  asm volatile("s_waitcnt vmcnt(0)" ::: "memory")
#define NOPX ((void)0)

// A-fragment loads: 4 m-frags x 2 k-slices from A-half HH of buffer CB.
#define LOAD_A(CB, HH) do { \
    const char* ap_ = &lds[CB][0][HH][0] + arow; \
    _Pragma("unroll") \
    for (int mi_ = 0; mi_ < 4; ++mi_) { \
        af[mi_][0] = *(const short8*)(ap_ + mi_*2048 + ck0); \
        af[mi_][1] = *(const short8*)(ap_ + mi_*2048 + ck1); \
    } } while (0)

// B-fragment loads: 2 n-frags x 2 k-slices from B-half HH of buffer CB.
#define LOAD_B(CB, HH, BF) do { \
    const char* bp_ = &lds[CB][1][HH][0] + brow; \
    _Pragma("unroll") \
    for (int ni_ = 0; ni_ < 2; ++ni_) { \
        BF[ni_][0] = *(const short8*)(bp_ + ni_*2048 + ck0); \
        BF[ni_][1] = *(const short8*)(bp_ + ni_*2048 + ck1); \
    } } while (0)

// One phase: {ds-reads | stage issue} ; bar ; lgkmcnt(0) ; 16 MFMA ; [vmcnt] ; bar
#define PHASE(LD1, LD2, STG, QM, QN, BF, VMW) do { \
    LD1; LD2; STG; \
    __builtin_amdgcn_s_barrier(); \
    asm volatile("s_waitcnt lgkmcnt(0)" ::: "memory"); \
    __builtin_amdgcn_sched_barrier(0); \
    __builtin_amdgcn_s_setprio(1); \
    _Pragma("unroll") \
    for (int mi_ = 0; mi_ < 4; ++mi_) \
    _Pragma("unroll") \
    for (int ni_ = 0; ni_ < 2; ++ni_) \
    _Pragma("unroll") \
    for (int kk_ = 0; kk_ < 2; ++kk_) \
        acc[(QM)*4+mi_][(QN)*2+ni_] = __builtin_amdgcn_mfma_f32_16x16x32_bf16( \
            af[mi_][kk_], BF[ni_][kk_], acc[(QM)*4+mi_][(QN)*2+ni_], 0, 0, 0); \
    __builtin_amdgcn_s_setprio(0); \
    VMW; \
    __builtin_amdgcn_s_barrier(); \
    __builtin_amdgcn_sched_barrier(0); \
} while (0)

// Tiles 0..NTX-1 come from (Ax,Wx) with row stride NTX*128 bytes;
// tiles NTX..NTX+NTZ-1 from (Az,Wz) with row stride NTZ*128 bytes.
// C[i,j] = sum_k A[i,k]*W[j,k]; output eta(C) (bf16, or fp32 if LAST).
template<int NTX, int NTZ, bool LAST>
__global__ void __launch_bounds__(512, 2)
lista_step(const unsigned short* __restrict__ Ax,
           const unsigned short* __restrict__ Wx,
           const unsigned short* __restrict__ Az,
           const unsigned short* __restrict__ Wz,
           const float* __restrict__ theta,
           unsigned short* __restrict__ Zout,
           float* __restrict__ Fout)
{
    constexpr int NT  = NTX + NTZ;     // total K-tiles of 64
    constexpr int NI  = NT / 2;        // main iterations (2 K-tiles each)
    constexpr int KBX = NTX * 128;     // X/We row stride (bytes)
    constexpr int KBZ = NTZ * 128;     // Z/S  row stride (bytes)
    constexpr int N   = 1024;

    // [buf][A=0/B=1][half][16KB]; half = permuted 128-row group so each half
    // is LDS-read in exactly one phase (A: bit6 of row; B: bit5 of row).
    __shared__ __align__(128) char lds[2][2][2][16384];

    const int t    = threadIdx.x;      // 0..511
    const int lane = t & 63;
    const int wave = t >> 6;           // 0..7
    const int wm   = wave >> 2;        // 0..1  (M half)
    const int wn   = wave & 3;         // 0..3  (N quarter)
    const int bm   = blockIdx.x;       // 0..63
    const int bn   = blockIdx.y;       // 0..3

    const char* Xb = (const char*)Ax + (size_t)bm * 256 * KBX;
    const char* Wb = (const char*)Wx + (size_t)bn * 256 * KBX;
    const char* Zb = (const char*)Az + (size_t)bm * 256 * KBZ;
    const char* Sb = (const char*)Wz + (size_t)bn * 256 * KBZ;

    // ---- staging constants: thread t handles chunks I = c*512+t (c=0,1),
    // compacted row rho = I>>3, slot = I&7, global k-chunk = slot ^ (rho&7).
    const int u    = t >> 3;                       // 0..63
    const int gb16 = ((t & 7) ^ (u & 7)) << 4;     // swizzled k-chunk byte off
    const int rA0  = u;                            // A: row = rA0+64h (+128 c=1)
    const int rB0  = (u & 31) + 2 * (u & 32);      // B: row = rB0+32h (+128 c=1)

    // ---- fragment-read constants
    const int rl   = lane & 15;
    const int q    = lane >> 4;                    // k-quad
    const int ck0  = ((q ^ (rl & 7)) << 4);        // kk=0 chunk byte (swizzled)
    const int ck1  = (((4 + q) ^ (rl & 7)) << 4);  // kk=1
    const int arow = (wm * 64 + rl) * 128;         // A compacted-row byte base
    const int brow = (wn * 32 + rl) * 128;         // B compacted-row byte base

    floatx4 acc[8][4];
#pragma unroll
    for (int i = 0; i < 8; ++i)
#pragma unroll
        for (int j = 0; j < 4; ++j) acc[i][j] = (floatx4){0.f, 0.f, 0.f, 0.f};

    short8 af[4][2], bf0[2][2], bf1[2][2];

    auto STAGE_A = [&](int buf, int h, int kt) {
        const char* base; int kb, ko;
        if (NTZ == 0 || kt < NTX) { base = Xb; kb = KBX; ko = kt * 128; }
        else                      { base = Zb; kb = KBZ; ko = (kt - NTX) * 128; }
        char* lp = &lds[buf][0][h][0] + t * 16;
        const size_t go = (size_t)(rA0 + 64 * h) * kb + ko + gb16;
        g2lds16(base + go, lp);
        g2lds16(base + go + (size_t)128 * kb, lp + 8192);
    };
    auto STAGE_B = [&](int buf, int h, int kt) {
        const char* base; int kb, ko;
        if (NTZ == 0 || kt < NTX) { base = Wb; kb = KBX; ko = kt * 128; }
        else                      { base = Sb; kb = KBZ; ko = (kt - NTX) * 128; }
        char* lp = &lds[buf][1][h][0] + t * 16;
        const size_t go = (size_t)(rB0 + 32 * h) * kb + ko + gb16;
        g2lds16(base + go, lp);
        g2lds16(base + go + (size_t)128 * kb, lp + 8192);
    };

    // ---- prologue: stage tile0 (buf0) and tile1 (buf1) fully; wait tile0.
    // 16 loads outstanding; vmcnt(8) drains tile0's 8 -> invariant at window
    // start: 8 outstanding = buf1's tile.
    STAGE_A(0, 0, 0); STAGE_B(0, 0, 0); STAGE_A(0, 1, 0); STAGE_B(0, 1, 0);
    STAGE_A(1, 0, 1); STAGE_B(1, 0, 1); STAGE_A(1, 1, 1); STAGE_B(1, 1, 1);
    VM8;
    __builtin_amdgcn_s_barrier();
    __builtin_amdgcn_sched_barrier(0);

    // ---- main loop. Window it: compute tiles a=2it (buf0, p1-4) and
    // b=2it+1 (buf1, p5-8); stage c=2it+2 into buf0 at p2-p4 (each region
    // staged the phase after its last ds_read) and d=2it+3 into buf1 at p6-p8.
    // Ledger (per-thread outstanding): start 8(b); p2 +4; p3 +2; p4 +2 =16;
    // VM8 drains b's 8 (landed before p5 reads buf1); p6 +4; p7 +2; p8 +2 =16;
    // VM8 drains c's 8 (landed before next p1 reads buf0). 4-phase lead on
    // every load; never vmcnt(0) in steady state.
#pragma unroll 1
    for (int it = 0; it < NI - 1; ++it) {
        const int c = 2 * it + 2, d = 2 * it + 3;
        PHASE(LOAD_A(0,0), LOAD_B(0,0,bf0), NOPX,                             0,0, bf0, NOPX);
        PHASE(LOAD_B(0,1,bf1), NOPX,        (STAGE_A(0,0,c), STAGE_B(0,0,c)), 0,1, bf1, NOPX);
        PHASE(LOAD_A(0,1), NOPX,            STAGE_B(0,1,c),                   1,1, bf1, NOPX);
        PHASE(NOPX, NOPX,                   STAGE_A(0,1,c),                   1,0, bf0, VM8);
        PHASE(LOAD_A(1,0), LOAD_B(1,0,bf0), NOPX,                             0,0, bf0, NOPX);
        PHASE(LOAD_B(1,1,bf1), NOPX,        (STAGE_A(1,0,d), STAGE_B(1,0,d)), 0,1, bf1, NOPX);
        PHASE(LOAD_A(1,1), NOPX,            STAGE_B(1,1,d),                   1,1, bf1, NOPX);
        PHASE(NOPX, NOPX,                   STAGE_A(1,1,d),                   1,0, bf0, VM8);
    }
    {   // last window: no future stages. At p4 only buf1's 8 remain -> VM0.
        PHASE(LOAD_A(0,0), LOAD_B(0,0,bf0), NOPX, 0,0, bf0, NOPX);
        PHASE(LOAD_B(0,1,bf1), NOPX,        NOPX, 0,1, bf1, NOPX);
        PHASE(LOAD_A(0,1), NOPX,            NOPX, 1,1, bf1, NOPX);
        PHASE(NOPX, NOPX,                   NOPX, 1,0, bf0, VM0);
        PHASE(LOAD_A(1,0), LOAD_B(1,0,bf0), NOPX, 0,0, bf0, NOPX);
        PHASE(LOAD_B(1,1,bf1), NOPX,        NOPX, 0,1, bf1, NOPX);
        PHASE(LOAD_A(1,1), NOPX,            NOPX, 1,1, bf1, NOPX);
        PHASE(NOPX, NOPX,                   NOPX, 1,0, bf0, NOPX);
    }

    // ---- epilogue: C/D layout col = lane&15, row = (lane>>4)*4 + reg.
    // Row-outer / ni-inner so the 4 x 32B chunks of each 128B output line are
    // written back-to-back (line completes before eviction -> no write RMW).
    const int colb = bn * 256 + wn * 64 + (lane & 15);
    const int rowb = bm * 256 + wm * 128 + ((lane >> 4) << 2);
    float th[4];
#pragma unroll
    for (int ni = 0; ni < 4; ++ni) th[ni] = theta[colb + ni * 16];
#pragma unroll
    for (int mi = 0; mi < 8; ++mi) {
#pragma unroll
        for (int v = 0; v < 4; ++v) {
            const size_t rb = (size_t)(rowb + mi * 16 + v) * N;
#pragma unroll
            for (int ni = 0; ni < 4; ++ni) {
                const size_t idx = rb + colb + ni * 16;
                const float c = acc[mi][ni][v];
                const float a = fabsf(c) - th[ni];
                const float z = a > 0.f ? (c > 0.f ? a : -a) : 0.f;
                if constexpr (LAST) {
                    Fout[idx] = z;
                } else {
                    __hip_bfloat16 hb = __float2bfloat16(z);
                    Zout[idx] = *(const unsigned short*)&hb;
                }
            }
        }
    }
}

__global__ void __launch_bounds__(256)
cvt4(const float* __restrict__ s, unsigned short* __restrict__ d, int n4)
{
    const int i = blockIdx.x * blockDim.x + threadIdx.x;
    if (i < n4) {
        const float4 v = ((const float4*)s)[i];
        ushort4 o;
        __hip_bfloat16 b;
        b = __float2bfloat16(v.x); o.x = *(unsigned short*)&b;
        b = __float2bfloat16(v.y); o.y = *(unsigned short*)&b;
        b = __float2bfloat16(v.z); o.z = *(unsigned short*)&b;
        b = __float2bfloat16(v.w); o.w = *(unsigned short*)&b;
        ((ushort4*)d)[i] = o;
    }
}

extern "C" void kernel_launch(void* const* d_in, const int* in_sizes, int n_in,
                              void* d_out, int out_size, void* d_ws, size_t ws_size,
                              hipStream_t stream) {
    (void)in_sizes; (void)n_in; (void)out_size; (void)ws_size;
    const float* X     = (const float*)d_in[0];  // 16384 x 256
    const float* We    = (const float*)d_in[1];  // 1024 x 256
    const float* S     = (const float*)d_in[2];  // 1024 x 1024
    const float* theta = (const float*)d_in[3];  // 1024
    float* out = (float*)d_out;                  // 16384 x 1024 fp32

    char* ws = (char*)d_ws;
    unsigned short* S_bf  = (unsigned short*)(ws);                           //  2 MB
    unsigned short* X_bf  = (unsigned short*)(ws + (size_t)2  * 1048576);    //  8 MB
    unsigned short* We_bf = (unsigned short*)(ws + (size_t)10 * 1048576);    // 0.5 MB
    unsigned short* Za    = (unsigned short*)(ws + (size_t)11 * 1048576);    // 32 MB
    unsigned short* Zb    = (unsigned short*)(ws + (size_t)43 * 1048576);    // 32 MB (total 75 MB)

    cvt4<<<dim3(1024), dim3(256), 0, stream>>>(S,  S_bf,  1024 * 1024 / 4);
    cvt4<<<dim3(4096), dim3(256), 0, stream>>>(X,  X_bf,  16384 * 256 / 4);
    cvt4<<<dim3(256),  dim3(256), 0, stream>>>(We, We_bf, 1024 * 256 / 4);

    const dim3 grid(64, 4), blk(512);

    // Z0 = eta(X @ We^T)            (K = 256)
    lista_step<4, 0, false><<<grid, blk, 0, stream>>>(
        X_bf, We_bf, nullptr, nullptr, theta, Za, nullptr);

    // steps 1..15: Z = eta([X,Z] @ [We,S]^T)   (K = 1280), ping-pong bf16
    unsigned short* zin = Za;
    unsigned short* zout = Zb;
    for (int tstep = 1; tstep <= 15; ++tstep) {
        lista_step<4, 16, false><<<grid, blk, 0, stream>>>(
            X_bf, We_bf, zin, S_bf, theta, zout, nullptr);
        unsigned short* tmp = zin; zin = zout; zout = tmp;
    }
    // step 16: write fp32 output directly
    lista_step<4, 16, true><<<grid, blk, 0, stream>>>(
        X_bf, We_bf, zin, S_bf, theta, nullptr, out);
}